// Round 6
// baseline (149.359 us; speedup 1.0000x reference)
//
#include <hip/hip_runtime.h>
#include <hip/hip_bf16.h>

// Problem constants
#define BB 2
#define LL 2048
#define DD 512
#define HH 8
#define HDM 64
#define SCALE 0.022097086912079608f    // 1/sqrt(2048)
#define QSCALE 0.03187935766f          // SCALE * log2(e)  (exp2-domain softmax)

typedef __hip_bfloat16 bf16;
typedef unsigned short u16;
typedef __attribute__((ext_vector_type(8))) short short8v;   // 8 bf16 (4 VGPRs)
typedef __attribute__((ext_vector_type(4))) float float4v;   // 4 fp32 acc

// Input element counts
#define XN  2097152    // 2*2048*512
#define WN  2359296    // 1536*512*3
#define BN  1536
#define FWN 262144     // 512*512
#define FBN 512

__device__ __forceinline__ float b2f(u16 u) {
    return __uint_as_float(((unsigned int)u) << 16);
}
__device__ __forceinline__ u16 f2u(float f) {
    bf16 h = __float2bfloat16(f);
    u16 r;
    __builtin_memcpy(&r, &h, 2);
    return r;
}
__device__ __forceinline__ uint4 pack8(const float* f) {
    uint4 p;
    p.x = (unsigned)f2u(f[0]) | ((unsigned)f2u(f[1]) << 16);
    p.y = (unsigned)f2u(f[2]) | ((unsigned)f2u(f[3]) << 16);
    p.z = (unsigned)f2u(f[4]) | ((unsigned)f2u(f[5]) << 16);
    p.w = (unsigned)f2u(f[6]) | ((unsigned)f2u(f[7]) << 16);
    return p;
}

// async 16-B global -> LDS copy (lds dest = wave-uniform base + lane*16)
__device__ __forceinline__ void gld_lds16(const u16* g, u16* l) {
    __builtin_amdgcn_global_load_lds(
        (const __attribute__((address_space(1))) unsigned int*)g,
        (__attribute__((address_space(3))) unsigned int*)l, 16, 0, 0);
}

// dtype detect (f32 vs bf16 inputs), computed locally per wave — all waves
// read the same first 256 half-words of raw x, so result is uniform and
// deterministic across all blocks/kernels.
__device__ __forceinline__ int detect_flag(const u16* __restrict__ xraw) {
    int bad = 0;
    int lane = threadIdx.x & 63;
    for (int i = lane; i < 256; i += 64) {
        float v = b2f(xraw[i]);
        if (!(fabsf(v) < 100.f)) bad = 1;   // catches NaN too
    }
    return (__ballot(bad) != 0ull) ? 1 : 0;
}

__device__ __forceinline__ void conv8(const void* src, u16* dst, size_t i, int flag) {
    if (flag) {
        const float* s = (const float*)src;
        float f[8];
        float4 a = *(const float4*)(s + i);
        float4 b = *(const float4*)(s + i + 4);
        f[0] = a.x; f[1] = a.y; f[2] = a.z; f[3] = a.w;
        f[4] = b.x; f[5] = b.y; f[6] = b.z; f[7] = b.w;
        *(uint4*)(dst + i) = pack8(f);
    } else {
        *(uint4*)(dst + i) = *(const uint4*)((const u16*)src + i);
    }
}

// -------------------------------------------------------------------------
// Kernel 0: unified prep — one launch, block-range branch:
//   [0,1024)    : x -> zero-guard-padded xp[B][2050][512] (+ guard rows)
//   [1024,1216) : cnn_w canonicalize + transpose via LDS (coalesced loads)
//   [1216,1345) : cnn_b + fc_w + fc_b converts
// -------------------------------------------------------------------------
__global__ __launch_bounds__(256) void prep_kernel(
    const void* __restrict__ xsrc, const void* __restrict__ wsrc,
    const void* __restrict__ bsrc, const void* __restrict__ fwsrc,
    const void* __restrict__ fbsrc,
    u16* __restrict__ xp, u16* __restrict__ wt,
    u16* __restrict__ bc, u16* __restrict__ fwc, u16* __restrict__ fbc)
{
    const int flag = detect_flag((const u16*)xsrc);
    const int bid = blockIdx.x;

    if (bid < 1024) {
        // ---- xpad ----
        int idx = bid * 256 + threadIdx.x;           // octet id, < 2*2048*64
        if (idx < 256) {
            int b2  = idx >> 7;
            int r2  = (idx >> 6) & 1;
            int c82 = (idx & 63) * 8;
            size_t off = ((size_t)(b2 * 2050 + (r2 ? 2049 : 0))) * 512 + c82;
            uint4 z = {0u, 0u, 0u, 0u};
            *(uint4*)(xp + off) = z;
        }
        int b   = idx / (LL * 64);
        int rem = idx - b * (LL * 64);
        int l   = rem >> 6;
        int c8  = (rem & 63) * 8;
        size_t si = ((size_t)(b * LL + l)) * 512 + c8;
        size_t di = ((size_t)(b * 2050 + l + 1)) * 512 + c8;
        if (flag) {
            const float* s = (const float*)xsrc;
            float f[8];
            float4 a = *(const float4*)(s + si);
            float4 bq = *(const float4*)(s + si + 4);
            f[0] = a.x; f[1] = a.y; f[2] = a.z; f[3] = a.w;
            f[4] = bq.x; f[5] = bq.y; f[6] = bq.z; f[7] = bq.w;
            *(uint4*)(xp + di) = pack8(f);
        } else {
            *(uint4*)(xp + di) = *(const uint4*)((const u16*)xsrc + si);
        }
    } else if (bid < 1216) {
        // ---- convw via LDS transpose: 8 o-rows per block, coalesced ----
        __shared__ u16 wl[8 * 1536];                 // 24 KB, [row][i*3+k]
        const int t  = threadIdx.x;
        const int o0 = (bid - 1024) * 8;
        if (flag) {
            const float4* s4 = (const float4*)((const float*)wsrc + (size_t)o0 * 1536);
#pragma unroll
            for (int v = 0; v < 12; ++v) {           // 3072 float4 total
                int i4 = v * 256 + t;
                float4 q = s4[i4];
                uint2 p;
                p.x = (unsigned)f2u(q.x) | ((unsigned)f2u(q.y) << 16);
                p.y = (unsigned)f2u(q.z) | ((unsigned)f2u(q.w) << 16);
                *(uint2*)&wl[i4 * 4] = p;
            }
        } else {
            const uint4* s8 = (const uint4*)((const u16*)wsrc + (size_t)o0 * 1536);
#pragma unroll
            for (int v = 0; v < 6; ++v) {            // 1536 uint4 total
                int i8 = v * 256 + t;
                *(uint4*)&wl[i8 * 8] = s8[i8];
            }
        }
        __syncthreads();
#pragma unroll
        for (int v = 0; v < 6; ++v) {                // 1536 output octets
            int oct = v * 256 + t;
            int row = oct / 192;
            int rem = oct - row * 192;
            int k   = rem >> 6;
            int i8  = rem & 63;
            u16 tmp[8];
#pragma unroll
            for (int j = 0; j < 8; ++j) tmp[j] = wl[row * 1536 + (i8 * 8 + j) * 3 + k];
            uint4 val;
            val.x = (unsigned)tmp[0] | ((unsigned)tmp[1] << 16);
            val.y = (unsigned)tmp[2] | ((unsigned)tmp[3] << 16);
            val.z = (unsigned)tmp[4] | ((unsigned)tmp[5] << 16);
            val.w = (unsigned)tmp[6] | ((unsigned)tmp[7] << 16);
            *(uint4*)(wt + (size_t)(o0 + row) * 1536 + k * 512 + i8 * 8) = val;
        }
    } else {
        // ---- small converts ----
        int o = (bid - 1216) * 256 + threadIdx.x;    // octet id
        if (o < BN / 8) {
            conv8(bsrc, bc, (size_t)o * 8, flag);
        } else if (o < BN / 8 + FWN / 8) {
            conv8(fwsrc, fwc, (size_t)(o - BN / 8) * 8, flag);
        } else if (o < BN / 8 + FWN / 8 + FBN / 8) {
            conv8(fbsrc, fbc, (size_t)(o - BN / 8 - FWN / 8) * 8, flag);
        }
    }
}

// -------------------------------------------------------------------------
// Kernel 1: conv GEMM — R12-verified form: 128x128 tiles, 384 blocks,
// m97-style K-loop (global_load_lds 16B, XOR bank swizzle, 1 barrier/chunk),
// LDS-transpose epilogue (coalesced qkbuf/vbuf writes), QSCALE fold into Q.
// V-columns are written in the tile-interleaved key order (verified R2) so
// the attention kernel's register-resident P^T feeds PV MFMAs directly.
// -------------------------------------------------------------------------
__global__ __launch_bounds__(256) void conv_mfma_kernel(
    const u16* __restrict__ xp,     // [B][2050][512] padded bf16
    const u16* __restrict__ wt,     // [1536][1536] = [o][k*512+i]
    const u16* __restrict__ bias,   // [1536]
    u16* __restrict__ qkbuf,        // [B*H][2][L][64]
    u16* __restrict__ vbuf)         // [B*H][64][L] (key-permuted, see above)
{
    __shared__ u16 smem[32768];     // 65536 B
    u16* Asb = smem;                // [2][128][64] unpadded, swizzled
    u16* Bsb = smem + 2 * 128 * 64; // [2][128][64] unpadded, swizzled
#define OTS 140
    u16* OT  = smem;                // [128][140] aliased after final sync

    const int blk = blockIdx.x;          // rt*12 + ct
    const int rt = blk / 12;
    const int ct = blk - rt * 12;
    const int b  = rt >> 4;
    const int l0 = (rt & 15) * 128;
    const int tid  = threadIdx.x;
    const int wave = tid >> 6;
    const int lane = tid & 63;
    const int quad = lane >> 4;
    const int l16  = lane & 15;
    const int e7   = l16 & 7;
    const int wx = wave & 1;             // n half
    const int wy = wave >> 1;            // m half

    float4v acc[4][4];
#pragma unroll
    for (int mt = 0; mt < 4; ++mt)
#pragma unroll
        for (int nt = 0; nt < 4; ++nt) acc[mt][nt] = (float4v){0.f, 0.f, 0.f, 0.f};

    const int rowW = wave * 32;
    const int lrow = lane >> 3;          // 0..7
    const int g8   = (((lane & 7) ^ lrow)) * 8;
    auto stage = [&](int kc, int buf) {
        const int slab = kc >> 3;                // conv tap k (0..2)
        const int i0   = (kc & 7) * 64;          // input-channel slice
        const u16* ga = xp + ((size_t)(b * 2050 + l0 + rowW + slab + lrow)) * 512 + i0 + g8;
        const u16* gb = wt + ((size_t)(ct * 128 + rowW + lrow)) * 1536 + kc * 64 + g8;
        u16* la = Asb + (size_t)(buf * 128 + rowW) * 64;
        u16* lb = Bsb + (size_t)(buf * 128 + rowW) * 64;
#pragma unroll
        for (int j = 0; j < 4; ++j) {
            gld_lds16(ga + (size_t)(j * 8) * 512,  la + (j * 8) * 64);
            gld_lds16(gb + (size_t)(j * 8) * 1536, lb + (j * 8) * 64);
        }
    };

    stage(0, 0);

    for (int kc = 0; kc < 24; ++kc) {
        const int cur = kc & 1;
        __syncthreads();   // drains vmcnt -> chunk kc staged; prev reads done

        if (kc < 23) stage(kc + 1, 1 - cur);

#pragma unroll
        for (int half = 0; half < 2; ++half) {
            const int p = ((half * 4 + quad) ^ e7) * 8;   // swizzled chunk
            short8v aF[4], bF[4];
#pragma unroll
            for (int mt = 0; mt < 4; ++mt)
                aF[mt] = *(const short8v*)&Asb[(size_t)(cur * 128 + wy * 64 + mt * 16 + l16) * 64 + p];
#pragma unroll
            for (int nt = 0; nt < 4; ++nt)
                bF[nt] = *(const short8v*)&Bsb[(size_t)(cur * 128 + wx * 64 + nt * 16 + l16) * 64 + p];
#pragma unroll
            for (int mt = 0; mt < 4; ++mt)
#pragma unroll
                for (int nt = 0; nt < 4; ++nt)
                    acc[mt][nt] = __builtin_amdgcn_mfma_f32_16x16x32_bf16(
                        aF[mt], bF[nt], acc[mt][nt], 0, 0, 0);
        }
    }

    // ---- epilogue stage 1: bias+swish(+QSCALE) in regs -> OT [128 l][128 o]
    __syncthreads();   // all LDS tile reads done; safe to alias as OT
    {
        const int tloc = (ct * 2 + wx) % 3;   // t for this wave's col group
#pragma unroll
        for (int nt = 0; nt < 4; ++nt) {
            int oc = wx * 64 + nt * 16 + l16;           // tile-local col
            float bb = b2f(bias[ct * 128 + oc]);
#pragma unroll
            for (int mt = 0; mt < 4; ++mt)
#pragma unroll
                for (int r = 0; r < 4; ++r) {
                    int lr = wy * 64 + mt * 16 + quad * 4 + r;   // tile-local row
                    float y = acc[mt][nt][r] + bb;
                    y = y / (1.f + __expf(-y));                  // swish
                    if (tloc == 0) y *= QSCALE;                  // fold scale*log2e into Q
                    OT[lr * OTS + oc] = f2u(y);
                }
        }
    }
    __syncthreads();

    // ---- epilogue stage 2: coalesced write-out per 64-col group
#pragma unroll
    for (int g = 0; g < 2; ++g) {
        int a  = ct * 2 + g;        // 64-col group index (0..23)
        int t  = a % 3;
        int bh = b * HH + a / 3;
        if (t != 2) {
            u16* base = qkbuf + ((size_t)((bh * 2 + t) * LL + l0)) * HDM;
#pragma unroll
            for (int it = 0; it < 4; ++it) {
                int idx = it * 256 + tid;       // 0..1023
                int l   = idx >> 3;             // 0..127
                int d8  = (idx & 7) * 8;        // 0..56
                uint4 val = *(const uint4*)&OT[l * OTS + g * 64 + d8];
                *(uint4*)(base + (size_t)l * HDM + d8) = val;
            }
        } else {
            u16* base = vbuf + ((size_t)(bh * HDM)) * LL + l0;
#pragma unroll
            for (int it = 0; it < 4; ++it) {
                int idx = it * 256 + tid;       // 0..1023
                int dd  = idx >> 4;             // 0..63
                int p   = idx & 15;             // 8-col group within 128 tile
                int l8  = p * 8;
                u16 tmp[8];
#pragma unroll
                for (int j = 0; j < 8; ++j) tmp[j] = OT[(l8 + j) * OTS + g * 64 + dd];
                // tile-interleaved key permute within each 32-key group:
                // orig w -> n = 8*((w>>2)&3) + 4*(w>>4) + (w&3)
                int a32 = p >> 2;                // 32-key group
                int pb_ = p & 3;
                int q2  = (2 * pb_) & 3;
                int h2  = pb_ >> 1;
                int n0  = 32 * a32 + 8 * q2 + 4 * h2;   // j=0..3 run
                uint2 v0, v1;
                v0.x = (unsigned)tmp[0] | ((unsigned)tmp[1] << 16);
                v0.y = (unsigned)tmp[2] | ((unsigned)tmp[3] << 16);
                v1.x = (unsigned)tmp[4] | ((unsigned)tmp[5] << 16);
                v1.y = (unsigned)tmp[6] | ((unsigned)tmp[7] << 16);
                *(uint2*)(base + (size_t)dd * LL + n0)     = v0;   // j=0..3
                *(uint2*)(base + (size_t)dd * LL + n0 + 8) = v1;   // j=4..7
            }
        }
    }
#undef OTS
}

// -------------------------------------------------------------------------
// Kernel 2: MFMA flash attention — quad-Q (64 queries/wave: every K/V LDS
// fragment read feeds 4 subgroups' MFMAs) + 4-way split-K (static softmax
// => partials purely additive; combine = 3 writer groups + kg0 accumulate).
// 256 blocks x 512 threads: wave = (kg = w>>1, qg = w&1); each kg
// double-buffers its own 64-key K[64][64]/V[64][64] tiles (128 KB LDS,
// 1 block/CU, 2 waves/SIMD). Register-resident P^T layout and key-permuted
// V consumption identical to the R3-verified dual-Q form.
// -------------------------------------------------------------------------
__global__ __launch_bounds__(512) void attn_mfma_kernel(
    const u16* __restrict__ qk,    // [B*H][2][L][64]
    const u16* __restrict__ v,     // [B*H][64][L] key-permuted
    u16* __restrict__ newv)        // [B][L][512]
{
    __shared__ u16 smem[65536];                                   // 128 KB pool
    u16 (*kts)[2][64][64] = (u16 (*)[2][64][64])smem;             // [kg][buf][key][d] 64 KB
    u16 (*vts)[2][64][64] = (u16 (*)[2][64][64])(smem + 32768);   // [kg][buf][d][key] 64 KB

    // bijective XCD swizzle (256 % 8 == 0): 16 blocks of one bh -> 2 bh/XCD
    const int lb = ((blockIdx.x & 7) << 5) + (blockIdx.x >> 3);
    const int bh = lb >> 4;              // b*8 + h
    const int qc = lb & 15;              // 128-query chunk
    const int b  = bh >> 3;
    const int h  = bh & 7;
    const int tid  = threadIdx.x;
    const int wave = tid >> 6;           // 0..7
    const int kg   = wave >> 1;          // split-K group 0..3
    const int qg   = wave & 1;           // query group 0..1
    const int lane = tid & 63;
    const int quad = lane >> 4;
    const int l16  = lane & 15;
    const int e7   = l16 & 7;

    const u16* qbase = qk + ((size_t)(bh * 2 + 0)) * LL * HDM;
    const u16* kbase = qk + ((size_t)(bh * 2 + 1)) * LL * HDM;
    const u16* vbase = v + (size_t)bh * HDM * LL;

    const int q0 = qc * 128 + qg * 64;   // wave's 64 queries (4 subgroups of 16)

    // Q as B-frag per subgroup: lane l16 = query col, k-slot quad*8+j = d
    short8v qfrag[4][2];
#pragma unroll
    for (int sg = 0; sg < 4; ++sg) {
        const u16* qr = qbase + (size_t)(q0 + sg * 16 + l16) * HDM + quad * 8;
        qfrag[sg][0] = *(const short8v*)(qr);
        qfrag[sg][1] = *(const short8v*)(qr + 32);
    }

    // ones-row A-frag for col-sum MFMA: A[row=l16][k]=1 iff row==0
    short8v vones;
    {
        short o1 = (l16 == 0) ? (short)0x3F80 : (short)0;
#pragma unroll
        for (int j = 0; j < 8; ++j) vones[j] = o1;
    }

    float4v oacc[4][4];                  // [sg][dt] out^T rows d, col=query l16
    float4v lacc[4];
#pragma unroll
    for (int sg = 0; sg < 4; ++sg) {
        lacc[sg] = (float4v){0.f, 0.f, 0.f, 0.f};
#pragma unroll
        for (int dt = 0; dt < 4; ++dt) oacc[sg][dt] = (float4v){0.f, 0.f, 0.f, 0.f};
    }

    // staging: 2 waves of a kgroup (qg 0/1) cooperate on K 64x64 and V 64x64.
    // LDS[row][chunk c] holds global chunk c ^ (row&7)  (row&7 == lane>>3).
    const int rw8 = lane >> 3;            // 0..7
    const int sw8 = ((lane & 7) ^ rw8) * 8;
    auto stage = [&](int ic, int buf) {
        const int m0 = ic * 64;
#pragma unroll
        for (int r = 0; r < 4; ++r) {
            const int row0 = r * 16 + qg * 8;
            gld_lds16(kbase + (size_t)(m0 + row0 + rw8) * HDM + sw8,
                      &kts[kg][buf][row0][0]);
            gld_lds16(vbase + (size_t)(row0 + rw8) * LL + m0 + sw8,
                      &vts[kg][buf][row0][0]);
        }
    };

    stage(kg, 0);   // kgroup kg handles chunks 4*i + kg, i = 0..7

    for (int i = 0; i < 8; ++i) {
        const int cur = i & 1;
        __syncthreads();   // drains vmcnt -> chunk staged; prev reads done

        if (i < 7) stage(4 * (i + 1) + kg, 1 - cur);

        // S^T = K.Q^T per sg; exp2 immediately (keeps s-live-range short)
        unsigned pk[4][4][2];
#pragma unroll
        for (int mt = 0; mt < 4; ++mt) {
            short8v b0 = *(const short8v*)&kts[kg][cur][mt * 16 + l16][((quad) ^ e7) * 8];
            short8v b1 = *(const short8v*)&kts[kg][cur][mt * 16 + l16][((quad + 4) ^ e7) * 8];
#pragma unroll
            for (int sg = 0; sg < 4; ++sg) {
                float4v t = (float4v){0.f, 0.f, 0.f, 0.f};
                t = __builtin_amdgcn_mfma_f32_16x16x32_bf16(b0, qfrag[sg][0], t, 0, 0, 0);
                t = __builtin_amdgcn_mfma_f32_16x16x32_bf16(b1, qfrag[sg][1], t, 0, 0, 0);
                float p0 = __builtin_amdgcn_exp2f(t[0]);
                float p1 = __builtin_amdgcn_exp2f(t[1]);
                float p2 = __builtin_amdgcn_exp2f(t[2]);
                float p3 = __builtin_amdgcn_exp2f(t[3]);
                pk[sg][mt][0] = (unsigned)f2u(p0) | ((unsigned)f2u(p1) << 16);
                pk[sg][mt][1] = (unsigned)f2u(p2) | ((unsigned)f2u(p3) << 16);
            }
        }

        // 2 PV K=32 blocks per 64-key chunk; each V A-frag read feeds 4 sg
#pragma unroll
        for (int mu = 0; mu < 2; ++mu) {
            short8v pb[4];
#pragma unroll
            for (int sg = 0; sg < 4; ++sg) {
                union { short8v v8; unsigned u[4]; } U;
                U.u[0] = pk[sg][2 * mu][0];
                U.u[1] = pk[sg][2 * mu][1];
                U.u[2] = pk[sg][2 * mu + 1][0];
                U.u[3] = pk[sg][2 * mu + 1][1];
                pb[sg] = U.v8;
                lacc[sg] = __builtin_amdgcn_mfma_f32_16x16x32_bf16(vones, pb[sg], lacc[sg], 0, 0, 0);
            }
#pragma unroll
            for (int dt = 0; dt < 4; ++dt) {
                short8v va = *(const short8v*)&vts[kg][cur][dt * 16 + l16][((mu * 4 + quad) ^ e7) * 8];
#pragma unroll
                for (int sg = 0; sg < 4; ++sg)
                    oacc[sg][dt] = __builtin_amdgcn_mfma_f32_16x16x32_bf16(va, pb[sg], oacc[sg][dt], 0, 0, 0);
            }
        }
    }

    // denom for query l16 sits in lacc[sg][0] of lane l16 (row 0 of D)
    float dnm[4];
#pragma unroll
    for (int sg = 0; sg < 4; ++sg) dnm[sg] = __shfl(lacc[sg][0], l16);

    // split-K combine: static softmax => oacc/denoms add directly.
    // xch: 3 regions (kg 1..3) x [qg 2][68 rows][64 lanes] f32 = 104,448 B
    __syncthreads();   // all tile reads done; alias pool as exchange
    float* xch = (float*)smem;
#define XRG (2 * 68 * 64)
    if (kg > 0) {
        float* rg = xch + (kg - 1) * XRG + qg * (68 * 64);
#pragma unroll
        for (int sg = 0; sg < 4; ++sg) {
#pragma unroll
            for (int dt = 0; dt < 4; ++dt)
#pragma unroll
                for (int r = 0; r < 4; ++r)
                    rg[((sg * 16 + dt * 4 + r) << 6) + lane] = oacc[sg][dt][r];
            rg[((64 + sg) << 6) + lane] = dnm[sg];
        }
    }
    __syncthreads();
    if (kg == 0) {
        u16* ob = newv + (size_t)b * LL * 512 + h * 64;
        const float* rg = xch + qg * (68 * 64);
#pragma unroll
        for (int sg = 0; sg < 4; ++sg) {
            float dsum = dnm[sg];
#pragma unroll
            for (int p = 0; p < 3; ++p) dsum += rg[p * XRG + ((64 + sg) << 6) + lane];
            float inv = 1.f / dsum;
            const size_t orow = (size_t)(q0 + sg * 16 + l16) * 512 + quad * 4;
#pragma unroll
            for (int dt = 0; dt < 4; ++dt) {
                float o[4];
#pragma unroll
                for (int r = 0; r < 4; ++r) {
                    o[r] = oacc[sg][dt][r];
#pragma unroll
                    for (int p = 0; p < 3; ++p)
                        o[r] += rg[p * XRG + ((sg * 16 + dt * 4 + r) << 6) + lane];
                }
                unsigned lo = (unsigned)f2u(o[0] * inv) | ((unsigned)f2u(o[1] * inv) << 16);
                unsigned hi = (unsigned)f2u(o[2] * inv) | ((unsigned)f2u(o[3] * inv) << 16);
                uint2 val; val.x = lo; val.y = hi;
                *(uint2*)(ob + orow + dt * 16) = val;
            }
        }
    }
#undef XRG
}

// -------------------------------------------------------------------------
// Kernel 3: MFMA FC + swish + residual + layernorm, fused — 512 threads
// (8 waves, 64 cols each => 2 waves/SIMD). The block's 16 newv rows are
// staged ONCE into LDS via global_load_lds (linear dest + inverse-XOR
// source, XOR on read => <=2-way banks). R5-verified.
// -------------------------------------------------------------------------
__global__ __launch_bounds__(512) void fc_ln_mfma_kernel(
    const u16* __restrict__ newv,    // [4096][512] bf16
    const u16* __restrict__ fcw,     // [512][512] bf16
    const u16* __restrict__ fcb,     // [512]
    const u16* __restrict__ xp,      // [B][2050][512] padded bf16
    const u16* __restrict__ xraw,    // raw x input (dtype detect)
    void* __restrict__ out)          // bf16 or f32 per flag
{
    const int flag = detect_flag(xraw);
    const int l0 = blockIdx.x * 16;
    const int tid  = threadIdx.x;
    const int wave = tid >> 6;           // 0..7
    const int lane = tid & 63;
    const int quad = lane >> 4;
    const int l16  = lane & 15;
    const int col0 = wave * 64;

    const int bb_ = l0 >> 11;   // batch (16-row tiles never straddle)
    const size_t xbase = ((size_t)(bb_ * 2050 + (l0 & 2047) + 1)) * 512;

    __shared__ u16 As[16][512];          // 16 KB staged newv rows
    __shared__ float psum[8][16], psq[8][16];

    // stage: wave w stages rows w and w+8 (64 x 16B chunks per row).
    // LDS chunk c of row holds global chunk c ^ (row&7).
#pragma unroll
    for (int r = 0; r < 2; ++r) {
        const int row = wave + r * 8;
        gld_lds16(newv + (size_t)(l0 + row) * 512 + ((lane ^ (row & 7)) * 8),
                  &As[row][0]);
    }
    __syncthreads();   // drains vmcnt

    // aF[kc] = rows l16, cols kc*32 + quad*8 (chunk p = kc*4+quad, XOR'd)
    short8v aF[16];
#pragma unroll
    for (int kc = 0; kc < 16; ++kc)
        aF[kc] = *(const short8v*)&As[l16][(((kc * 4 + quad)) ^ (l16 & 7)) * 8];

    float4v acc[4];
#pragma unroll
    for (int nt = 0; nt < 4; ++nt) acc[nt] = (float4v){0.f, 0.f, 0.f, 0.f};

#pragma unroll
    for (int nt = 0; nt < 4; ++nt) {
        const u16* brow = fcw + (size_t)(col0 + nt * 16 + l16) * 512 + quad * 8;
#pragma unroll
        for (int kc = 0; kc < 16; ++kc) {
            short8v bF = *(const short8v*)(brow + kc * 32);
            acc[nt] = __builtin_amdgcn_mfma_f32_16x16x32_bf16(aF[kc], bF, acc[nt], 0, 0, 0);
        }
    }

    float z[4][4];
    float rs[4] = {0.f, 0.f, 0.f, 0.f}, rq[4] = {0.f, 0.f, 0.f, 0.f};
#pragma unroll
    for (int nt = 0; nt < 4; ++nt) {
        int col = col0 + nt * 16 + l16;
        float bb = b2f(fcb[col]);
#pragma unroll
        for (int r = 0; r < 4; ++r) {
            int row = quad * 4 + r;
            float y = acc[nt][r] + bb;
            float sw = y / (1.f + __expf(-y));    // swish
            float xv = b2f(xp[xbase + (size_t)row * 512 + col]);
            float zz = xv * 2.f + sw;
            z[nt][r] = zz;
            rs[r] += zz;
            rq[r] += zz * zz;
        }
    }
#pragma unroll
    for (int msk = 1; msk <= 8; msk <<= 1)
#pragma unroll
        for (int r = 0; r < 4; ++r) {
            rs[r] += __shfl_xor(rs[r], msk);
            rq[r] += __shfl_xor(rq[r], msk);
        }
    if (l16 == 0) {
#pragma unroll
        for (int r = 0; r < 4; ++r) {
            psum[wave][quad * 4 + r] = rs[r];
            psq[wave][quad * 4 + r]  = rq[r];
        }
    }
    __syncthreads();

    float mu[4], inv[4];
#pragma unroll
    for (int r = 0; r < 4; ++r) {
        int row = quad * 4 + r;
        float s = 0.f, q = 0.f;
#pragma unroll
        for (int w = 0; w < 8; ++w) { s += psum[w][row]; q += psq[w][row]; }
        float m = s * (1.f / 512.f);
        float var = q * (1.f / 512.f) - m * m;
        mu[r] = m;
        inv[r] = rsqrtf(var + 1e-5f);
    }

#pragma unroll
    for (int nt = 0; nt < 4; ++nt) {
        int col = col0 + nt * 16 + l16;
#pragma unroll
        for (int r = 0; r < 4; ++r) {
            int row = quad * 4 + r;
            float val = (z[nt][r] - mu[r]) * inv[r];
            if (flag) ((float*)out)[(size_t)(l0 + row) * 512 + col] = val;
            else      ((u16*)out)[(size_t)(l0 + row) * 512 + col] = f2u(val);
        }
    }
}

extern "C" void kernel_launch(void* const* d_in, const int* in_sizes, int n_in,
                              void* d_out, int out_size, void* d_ws, size_t ws_size,
                              hipStream_t stream) {
    (void)in_sizes; (void)n_in; (void)out_size; (void)ws_size;

    char* ws = (char*)d_ws;
    u16* xp   = (u16*)(ws + 256);        // [2][2050][512] 4,198,400 B -> ends 4,198,656
    u16* wtc  = (u16*)(ws + 4198656);    // [1536][1536] 4,718,592 B  -> ends 8,917,248
    u16* bc   = (u16*)(ws + 8917248);    // 3,072 B  -> ends 8,920,320
    u16* fwc  = (u16*)(ws + 8920320);    // 524,288 B -> ends 9,444,608
    u16* fbc  = (u16*)(ws + 9444608);    // 1,024 B  -> ends 9,445,632
    u16* qkb  = (u16*)(ws + 9445632);    // [16][2][2048][64] = 8 MB -> ends 17,834,240
    u16* vb   = (u16*)(ws + 17834240);   // [16][64][2048]    = 4 MB -> ends 22,028,544
    u16* nvc  = (u16*)(ws + 22028544);   // [2][2048][512]    = 4 MB -> ends 26,222,848

    // unified prep: 1024 (xpad) + 192 (convw via LDS) + 129 (small) = 1345
    prep_kernel<<<dim3(1345), dim3(256), 0, stream>>>(
        d_in[0], d_in[1], d_in[2], d_in[3], d_in[4],
        xp, wtc, bc, fwc, fbc);

    conv_mfma_kernel<<<dim3(32 * 12), dim3(256), 0, stream>>>(xp, wtc, bc, qkb, vb);
    attn_mfma_kernel<<<dim3(256), dim3(512), 0, stream>>>(qkb, vb, nvc);
    fc_ln_mfma_kernel<<<dim3(256), dim3(512), 0, stream>>>(
        nvc, fwc, fbc, xp, (const u16*)d_in[0], d_out);
}

// Round 7
// 145.793 us; speedup vs baseline: 1.0245x; 1.0245x over previous
//
#include <hip/hip_runtime.h>
#include <hip/hip_bf16.h>

// Problem constants
#define BB 2
#define LL 2048
#define DD 512
#define HH 8
#define HDM 64
#define SCALE 0.022097086912079608f    // 1/sqrt(2048)
#define QSCALE 0.03187935766f          // SCALE * log2(e)  (exp2-domain softmax)

typedef __hip_bfloat16 bf16;
typedef unsigned short u16;
typedef __attribute__((ext_vector_type(8))) short short8v;   // 8 bf16 (4 VGPRs)
typedef __attribute__((ext_vector_type(4))) float float4v;   // 4 fp32 acc

// Input element counts
#define XN  2097152    // 2*2048*512
#define WN  2359296    // 1536*512*3
#define BN  1536
#define FWN 262144     // 512*512
#define FBN 512

__device__ __forceinline__ float b2f(u16 u) {
    return __uint_as_float(((unsigned int)u) << 16);
}
__device__ __forceinline__ u16 f2u(float f) {
    bf16 h = __float2bfloat16(f);
    u16 r;
    __builtin_memcpy(&r, &h, 2);
    return r;
}
__device__ __forceinline__ uint4 pack8(const float* f) {
    uint4 p;
    p.x = (unsigned)f2u(f[0]) | ((unsigned)f2u(f[1]) << 16);
    p.y = (unsigned)f2u(f[2]) | ((unsigned)f2u(f[3]) << 16);
    p.z = (unsigned)f2u(f[4]) | ((unsigned)f2u(f[5]) << 16);
    p.w = (unsigned)f2u(f[6]) | ((unsigned)f2u(f[7]) << 16);
    return p;
}

// async 16-B global -> LDS copy (lds dest = wave-uniform base + lane*16)
__device__ __forceinline__ void gld_lds16(const u16* g, u16* l) {
    __builtin_amdgcn_global_load_lds(
        (const __attribute__((address_space(1))) unsigned int*)g,
        (__attribute__((address_space(3))) unsigned int*)l, 16, 0, 0);
}

// dtype detect (f32 vs bf16 inputs), computed locally per wave — all waves
// read the same first 256 half-words of raw x, so result is uniform and
// deterministic across all blocks/kernels.
__device__ __forceinline__ int detect_flag(const u16* __restrict__ xraw) {
    int bad = 0;
    int lane = threadIdx.x & 63;
    for (int i = lane; i < 256; i += 64) {
        float v = b2f(xraw[i]);
        if (!(fabsf(v) < 100.f)) bad = 1;   // catches NaN too
    }
    return (__ballot(bad) != 0ull) ? 1 : 0;
}

__device__ __forceinline__ void conv8(const void* src, u16* dst, size_t i, int flag) {
    if (flag) {
        const float* s = (const float*)src;
        float f[8];
        float4 a = *(const float4*)(s + i);
        float4 b = *(const float4*)(s + i + 4);
        f[0] = a.x; f[1] = a.y; f[2] = a.z; f[3] = a.w;
        f[4] = b.x; f[5] = b.y; f[6] = b.z; f[7] = b.w;
        *(uint4*)(dst + i) = pack8(f);
    } else {
        *(uint4*)(dst + i) = *(const uint4*)((const u16*)src + i);
    }
}

// -------------------------------------------------------------------------
// Kernel 0: unified prep — one launch, block-range branch:
//   [0,1024)    : x -> zero-guard-padded xp[B][2050][512] (+ guard rows)
//   [1024,1216) : cnn_w canonicalize + transpose via LDS (coalesced loads)
//   [1216,1345) : cnn_b + fc_w + fc_b converts
// -------------------------------------------------------------------------
__global__ __launch_bounds__(256) void prep_kernel(
    const void* __restrict__ xsrc, const void* __restrict__ wsrc,
    const void* __restrict__ bsrc, const void* __restrict__ fwsrc,
    const void* __restrict__ fbsrc,
    u16* __restrict__ xp, u16* __restrict__ wt,
    u16* __restrict__ bc, u16* __restrict__ fwc, u16* __restrict__ fbc)
{
    const int flag = detect_flag((const u16*)xsrc);
    const int bid = blockIdx.x;

    if (bid < 1024) {
        // ---- xpad ----
        int idx = bid * 256 + threadIdx.x;           // octet id, < 2*2048*64
        if (idx < 256) {
            int b2  = idx >> 7;
            int r2  = (idx >> 6) & 1;
            int c82 = (idx & 63) * 8;
            size_t off = ((size_t)(b2 * 2050 + (r2 ? 2049 : 0))) * 512 + c82;
            uint4 z = {0u, 0u, 0u, 0u};
            *(uint4*)(xp + off) = z;
        }
        int b   = idx / (LL * 64);
        int rem = idx - b * (LL * 64);
        int l   = rem >> 6;
        int c8  = (rem & 63) * 8;
        size_t si = ((size_t)(b * LL + l)) * 512 + c8;
        size_t di = ((size_t)(b * 2050 + l + 1)) * 512 + c8;
        if (flag) {
            const float* s = (const float*)xsrc;
            float f[8];
            float4 a = *(const float4*)(s + si);
            float4 bq = *(const float4*)(s + si + 4);
            f[0] = a.x; f[1] = a.y; f[2] = a.z; f[3] = a.w;
            f[4] = bq.x; f[5] = bq.y; f[6] = bq.z; f[7] = bq.w;
            *(uint4*)(xp + di) = pack8(f);
        } else {
            *(uint4*)(xp + di) = *(const uint4*)((const u16*)xsrc + si);
        }
    } else if (bid < 1216) {
        // ---- convw via LDS transpose: 8 o-rows per block, coalesced ----
        __shared__ u16 wl[8 * 1536];                 // 24 KB, [row][i*3+k]
        const int t  = threadIdx.x;
        const int o0 = (bid - 1024) * 8;
        if (flag) {
            const float4* s4 = (const float4*)((const float*)wsrc + (size_t)o0 * 1536);
#pragma unroll
            for (int v = 0; v < 12; ++v) {           // 3072 float4 total
                int i4 = v * 256 + t;
                float4 q = s4[i4];
                uint2 p;
                p.x = (unsigned)f2u(q.x) | ((unsigned)f2u(q.y) << 16);
                p.y = (unsigned)f2u(q.z) | ((unsigned)f2u(q.w) << 16);
                *(uint2*)&wl[i4 * 4] = p;
            }
        } else {
            const uint4* s8 = (const uint4*)((const u16*)wsrc + (size_t)o0 * 1536);
#pragma unroll
            for (int v = 0; v < 6; ++v) {            // 1536 uint4 total
                int i8 = v * 256 + t;
                *(uint4*)&wl[i8 * 8] = s8[i8];
            }
        }
        __syncthreads();
#pragma unroll
        for (int v = 0; v < 6; ++v) {                // 1536 output octets
            int oct = v * 256 + t;
            int row = oct / 192;
            int rem = oct - row * 192;
            int k   = rem >> 6;
            int i8  = rem & 63;
            u16 tmp[8];
#pragma unroll
            for (int j = 0; j < 8; ++j) tmp[j] = wl[row * 1536 + (i8 * 8 + j) * 3 + k];
            uint4 val;
            val.x = (unsigned)tmp[0] | ((unsigned)tmp[1] << 16);
            val.y = (unsigned)tmp[2] | ((unsigned)tmp[3] << 16);
            val.z = (unsigned)tmp[4] | ((unsigned)tmp[5] << 16);
            val.w = (unsigned)tmp[6] | ((unsigned)tmp[7] << 16);
            *(uint4*)(wt + (size_t)(o0 + row) * 1536 + k * 512 + i8 * 8) = val;
        }
    } else {
        // ---- small converts ----
        int o = (bid - 1216) * 256 + threadIdx.x;    // octet id
        if (o < BN / 8) {
            conv8(bsrc, bc, (size_t)o * 8, flag);
        } else if (o < BN / 8 + FWN / 8) {
            conv8(fwsrc, fwc, (size_t)(o - BN / 8) * 8, flag);
        } else if (o < BN / 8 + FWN / 8 + FBN / 8) {
            conv8(fbsrc, fbc, (size_t)(o - BN / 8 - FWN / 8) * 8, flag);
        }
    }
}

// -------------------------------------------------------------------------
// Kernel 1: conv GEMM — re-tiled 128x192 x 512 threads => 256 blocks
// (1/CU exact, 2 waves/SIMD on EVERY CU vs the old 384-block 75-85% util).
// Same verified inner algebra: m97 K-loop (global_load_lds 16B, XOR bank
// swizzle, 1 barrier/chunk), 16x16x32 MFMA frags, identical K-chunk order
// (bitwise-same accumulation). 192 cols = one head's {q,k,v}: bh = b*8+ct,
// t = col-group g directly. V written in tile-interleaved key order
// (verified R2) for the attention kernel's register-resident P^T.
// -------------------------------------------------------------------------
__global__ __launch_bounds__(512) void conv_mfma_kernel(
    const u16* __restrict__ xp,     // [B][2050][512] padded bf16
    const u16* __restrict__ wt,     // [1536][1536] = [o][k*512+i]
    const u16* __restrict__ bias,   // [1536]
    u16* __restrict__ qkbuf,        // [B*H][2][L][64]
    u16* __restrict__ vbuf)         // [B*H][64][L] (key-permuted, see above)
{
    __shared__ u16 smem[40960];     // 81920 B
    u16* Asb = smem;                // [2][128][64] unpadded, swizzled (32 KB)
    u16* Bsb = smem + 16384;        // [2][192][64] unpadded, swizzled (48 KB)
#define OTS 204
    u16* OT  = smem;                // [128][204] aliased after final sync

    const int blk = blockIdx.x;          // rt*8 + ct
    const int rt = blk >> 3;
    const int ct = blk & 7;
    const int b  = rt >> 4;
    const int l0 = (rt & 15) * 128;
    const int tid  = threadIdx.x;
    const int wave = tid >> 6;           // 0..7
    const int lane = tid & 63;
    const int quad = lane >> 4;
    const int l16  = lane & 15;
    const int e7   = l16 & 7;
    const int wm = wave >> 2;            // M half (rows wm*64)
    const int wn = wave & 3;             // N quarter (cols wn*48)

    float4v acc[4][3];
#pragma unroll
    for (int mt = 0; mt < 4; ++mt)
#pragma unroll
        for (int nt = 0; nt < 3; ++nt) acc[mt][nt] = (float4v){0.f, 0.f, 0.f, 0.f};

    const int lrow = lane >> 3;          // 0..7
    const int g8   = (((lane & 7) ^ lrow)) * 8;
    auto stage = [&](int kc, int buf) {
        const int slab = kc >> 3;                // conv tap k (0..2)
        const int i0   = (kc & 7) * 64;          // input-channel slice
        // A: 128 rows, wave w stages rows w*16 + j*8 (+lrow)
#pragma unroll
        for (int j = 0; j < 2; ++j) {
            const int r0 = wave * 16 + j * 8;
            gld_lds16(xp + ((size_t)(b * 2050 + l0 + r0 + slab + lrow)) * 512 + i0 + g8,
                      Asb + (size_t)(buf * 128 + r0) * 64);
        }
        // B: 192 rows, wave w stages rows w*24 + j*8 (+lrow)
#pragma unroll
        for (int j = 0; j < 3; ++j) {
            const int r0 = wave * 24 + j * 8;
            gld_lds16(wt + ((size_t)(ct * 192 + r0 + lrow)) * 1536 + kc * 64 + g8,
                      Bsb + (size_t)(buf * 192 + r0) * 64);
        }
    };

    stage(0, 0);

    for (int kc = 0; kc < 24; ++kc) {
        const int cur = kc & 1;
        __syncthreads();   // drains vmcnt -> chunk kc staged; prev reads done

        if (kc < 23) stage(kc + 1, 1 - cur);

#pragma unroll
        for (int half = 0; half < 2; ++half) {
            const int p = ((half * 4 + quad) ^ e7) * 8;   // swizzled chunk
            short8v aF[4], bF[3];
#pragma unroll
            for (int mt = 0; mt < 4; ++mt)
                aF[mt] = *(const short8v*)&Asb[(size_t)(cur * 128 + wm * 64 + mt * 16 + l16) * 64 + p];
#pragma unroll
            for (int nt = 0; nt < 3; ++nt)
                bF[nt] = *(const short8v*)&Bsb[(size_t)(cur * 192 + wn * 48 + nt * 16 + l16) * 64 + p];
#pragma unroll
            for (int mt = 0; mt < 4; ++mt)
#pragma unroll
                for (int nt = 0; nt < 3; ++nt)
                    acc[mt][nt] = __builtin_amdgcn_mfma_f32_16x16x32_bf16(
                        aF[mt], bF[nt], acc[mt][nt], 0, 0, 0);
        }
    }

    // ---- epilogue stage 1: bias+swish(+QSCALE) in regs -> OT [128 l][192 o]
    __syncthreads();   // all LDS tile reads done; safe to alias as OT
    {
#pragma unroll
        for (int nt = 0; nt < 3; ++nt) {
            int oc = wn * 48 + nt * 16 + l16;           // tile-local col (0..191)
            float bb = b2f(bias[ct * 192 + oc]);
#pragma unroll
            for (int mt = 0; mt < 4; ++mt)
#pragma unroll
                for (int r = 0; r < 4; ++r) {
                    int lr = wm * 64 + mt * 16 + quad * 4 + r;   // tile-local row
                    float y = acc[mt][nt][r] + bb;
                    y = y / (1.f + __expf(-y));                  // swish
                    if (oc < 64) y *= QSCALE;                    // Q group: fold scale*log2e
                    OT[lr * OTS + oc] = f2u(y);
                }
        }
    }
    __syncthreads();

    // ---- epilogue stage 2: coalesced write-out per 64-col group (g = t)
    const int bh = b * HH + ct;          // 192 cols = head ct's {q,k,v}
#pragma unroll
    for (int g = 0; g < 3; ++g) {
        if (g != 2) {
            u16* base = qkbuf + ((size_t)((bh * 2 + g) * LL + l0)) * HDM;
#pragma unroll
            for (int it = 0; it < 2; ++it) {
                int idx = it * 512 + tid;       // 0..1023
                int l   = idx >> 3;             // 0..127
                int d8  = (idx & 7) * 8;        // 0..56
                uint4 val = *(const uint4*)&OT[l * OTS + g * 64 + d8];
                *(uint4*)(base + (size_t)l * HDM + d8) = val;
            }
        } else {
            u16* base = vbuf + ((size_t)(bh * HDM)) * LL + l0;
#pragma unroll
            for (int it = 0; it < 2; ++it) {
                int idx = it * 512 + tid;       // 0..1023
                int dd  = idx >> 4;             // 0..63
                int p   = idx & 15;             // 8-row group within 128 tile
                int l8  = p * 8;
                u16 tmp[8];
#pragma unroll
                for (int j = 0; j < 8; ++j) tmp[j] = OT[(l8 + j) * OTS + g * 64 + dd];
                // tile-interleaved key permute within each 32-key group:
                // orig w -> n = 8*((w>>2)&3) + 4*(w>>4) + (w&3)
                int a32 = p >> 2;                // 32-key group
                int pb_ = p & 3;
                int q2  = (2 * pb_) & 3;
                int h2  = pb_ >> 1;
                int n0  = 32 * a32 + 8 * q2 + 4 * h2;   // j=0..3 run
                uint2 v0, v1;
                v0.x = (unsigned)tmp[0] | ((unsigned)tmp[1] << 16);
                v0.y = (unsigned)tmp[2] | ((unsigned)tmp[3] << 16);
                v1.x = (unsigned)tmp[4] | ((unsigned)tmp[5] << 16);
                v1.y = (unsigned)tmp[6] | ((unsigned)tmp[7] << 16);
                *(uint2*)(base + (size_t)dd * LL + n0)     = v0;   // j=0..3
                *(uint2*)(base + (size_t)dd * LL + n0 + 8) = v1;   // j=4..7
            }
        }
    }
#undef OTS
}

// -------------------------------------------------------------------------
// Kernel 2: MFMA flash attention — quad-Q (64 queries/wave: every K/V LDS
// fragment read feeds 4 subgroups' MFMAs) + 4-way split-K (static softmax
// => partials purely additive; combine = 3 writer groups + kg0 accumulate).
// 256 blocks x 512 threads: wave = (kg = w>>1, qg = w&1); each kg
// double-buffers its own 64-key K[64][64]/V[64][64] tiles (128 KB LDS,
// 1 block/CU, 2 waves/SIMD). Register-resident P^T layout and key-permuted
// V consumption identical to the R3-verified dual-Q form. R6-verified.
// -------------------------------------------------------------------------
__global__ __launch_bounds__(512) void attn_mfma_kernel(
    const u16* __restrict__ qk,    // [B*H][2][L][64]
    const u16* __restrict__ v,     // [B*H][64][L] key-permuted
    u16* __restrict__ newv)        // [B][L][512]
{
    __shared__ u16 smem[65536];                                   // 128 KB pool
    u16 (*kts)[2][64][64] = (u16 (*)[2][64][64])smem;             // [kg][buf][key][d] 64 KB
    u16 (*vts)[2][64][64] = (u16 (*)[2][64][64])(smem + 32768);   // [kg][buf][d][key] 64 KB

    // bijective XCD swizzle (256 % 8 == 0): 16 blocks of one bh -> 2 bh/XCD
    const int lb = ((blockIdx.x & 7) << 5) + (blockIdx.x >> 3);
    const int bh = lb >> 4;              // b*8 + h
    const int qc = lb & 15;              // 128-query chunk
    const int b  = bh >> 3;
    const int h  = bh & 7;
    const int tid  = threadIdx.x;
    const int wave = tid >> 6;           // 0..7
    const int kg   = wave >> 1;          // split-K group 0..3
    const int qg   = wave & 1;           // query group 0..1
    const int lane = tid & 63;
    const int quad = lane >> 4;
    const int l16  = lane & 15;
    const int e7   = l16 & 7;

    const u16* qbase = qk + ((size_t)(bh * 2 + 0)) * LL * HDM;
    const u16* kbase = qk + ((size_t)(bh * 2 + 1)) * LL * HDM;
    const u16* vbase = v + (size_t)bh * HDM * LL;

    const int q0 = qc * 128 + qg * 64;   // wave's 64 queries (4 subgroups of 16)

    // Q as B-frag per subgroup: lane l16 = query col, k-slot quad*8+j = d
    short8v qfrag[4][2];
#pragma unroll
    for (int sg = 0; sg < 4; ++sg) {
        const u16* qr = qbase + (size_t)(q0 + sg * 16 + l16) * HDM + quad * 8;
        qfrag[sg][0] = *(const short8v*)(qr);
        qfrag[sg][1] = *(const short8v*)(qr + 32);
    }

    // ones-row A-frag for col-sum MFMA: A[row=l16][k]=1 iff row==0
    short8v vones;
    {
        short o1 = (l16 == 0) ? (short)0x3F80 : (short)0;
#pragma unroll
        for (int j = 0; j < 8; ++j) vones[j] = o1;
    }

    float4v oacc[4][4];                  // [sg][dt] out^T rows d, col=query l16
    float4v lacc[4];
#pragma unroll
    for (int sg = 0; sg < 4; ++sg) {
        lacc[sg] = (float4v){0.f, 0.f, 0.f, 0.f};
#pragma unroll
        for (int dt = 0; dt < 4; ++dt) oacc[sg][dt] = (float4v){0.f, 0.f, 0.f, 0.f};
    }

    // staging: 2 waves of a kgroup (qg 0/1) cooperate on K 64x64 and V 64x64.
    // LDS[row][chunk c] holds global chunk c ^ (row&7)  (row&7 == lane>>3).
    const int rw8 = lane >> 3;            // 0..7
    const int sw8 = ((lane & 7) ^ rw8) * 8;
    auto stage = [&](int ic, int buf) {
        const int m0 = ic * 64;
#pragma unroll
        for (int r = 0; r < 4; ++r) {
            const int row0 = r * 16 + qg * 8;
            gld_lds16(kbase + (size_t)(m0 + row0 + rw8) * HDM + sw8,
                      &kts[kg][buf][row0][0]);
            gld_lds16(vbase + (size_t)(row0 + rw8) * LL + m0 + sw8,
                      &vts[kg][buf][row0][0]);
        }
    };

    stage(kg, 0);   // kgroup kg handles chunks 4*i + kg, i = 0..7

    for (int i = 0; i < 8; ++i) {
        const int cur = i & 1;
        __syncthreads();   // drains vmcnt -> chunk staged; prev reads done

        if (i < 7) stage(4 * (i + 1) + kg, 1 - cur);

        // S^T = K.Q^T per sg; exp2 immediately (keeps s-live-range short)
        unsigned pk[4][4][2];
#pragma unroll
        for (int mt = 0; mt < 4; ++mt) {
            short8v b0 = *(const short8v*)&kts[kg][cur][mt * 16 + l16][((quad) ^ e7) * 8];
            short8v b1 = *(const short8v*)&kts[kg][cur][mt * 16 + l16][((quad + 4) ^ e7) * 8];
#pragma unroll
            for (int sg = 0; sg < 4; ++sg) {
                float4v t = (float4v){0.f, 0.f, 0.f, 0.f};
                t = __builtin_amdgcn_mfma_f32_16x16x32_bf16(b0, qfrag[sg][0], t, 0, 0, 0);
                t = __builtin_amdgcn_mfma_f32_16x16x32_bf16(b1, qfrag[sg][1], t, 0, 0, 0);
                float p0 = __builtin_amdgcn_exp2f(t[0]);
                float p1 = __builtin_amdgcn_exp2f(t[1]);
                float p2 = __builtin_amdgcn_exp2f(t[2]);
                float p3 = __builtin_amdgcn_exp2f(t[3]);
                pk[sg][mt][0] = (unsigned)f2u(p0) | ((unsigned)f2u(p1) << 16);
                pk[sg][mt][1] = (unsigned)f2u(p2) | ((unsigned)f2u(p3) << 16);
            }
        }

        // 2 PV K=32 blocks per 64-key chunk; each V A-frag read feeds 4 sg
#pragma unroll
        for (int mu = 0; mu < 2; ++mu) {
            short8v pb[4];
#pragma unroll
            for (int sg = 0; sg < 4; ++sg) {
                union { short8v v8; unsigned u[4]; } U;
                U.u[0] = pk[sg][2 * mu][0];
                U.u[1] = pk[sg][2 * mu][1];
                U.u[2] = pk[sg][2 * mu + 1][0];
                U.u[3] = pk[sg][2 * mu + 1][1];
                pb[sg] = U.v8;
                lacc[sg] = __builtin_amdgcn_mfma_f32_16x16x32_bf16(vones, pb[sg], lacc[sg], 0, 0, 0);
            }
#pragma unroll
            for (int dt = 0; dt < 4; ++dt) {
                short8v va = *(const short8v*)&vts[kg][cur][dt * 16 + l16][((mu * 4 + quad) ^ e7) * 8];
#pragma unroll
                for (int sg = 0; sg < 4; ++sg)
                    oacc[sg][dt] = __builtin_amdgcn_mfma_f32_16x16x32_bf16(va, pb[sg], oacc[sg][dt], 0, 0, 0);
            }
        }
    }

    // denom for query l16 sits in lacc[sg][0] of lane l16 (row 0 of D)
    float dnm[4];
#pragma unroll
    for (int sg = 0; sg < 4; ++sg) dnm[sg] = __shfl(lacc[sg][0], l16);

    // split-K combine: static softmax => oacc/denoms add directly.
    // xch: 3 regions (kg 1..3) x [qg 2][68 rows][64 lanes] f32 = 104,448 B
    __syncthreads();   // all tile reads done; alias pool as exchange
    float* xch = (float*)smem;
#define XRG (2 * 68 * 64)
    if (kg > 0) {
        float* rg = xch + (kg - 1) * XRG + qg * (68 * 64);
#pragma unroll
        for (int sg = 0; sg < 4; ++sg) {
#pragma unroll
            for (int dt = 0; dt < 4; ++dt)
#pragma unroll
                for (int r = 0; r < 4; ++r)
                    rg[((sg * 16 + dt * 4 + r) << 6) + lane] = oacc[sg][dt][r];
            rg[((64 + sg) << 6) + lane] = dnm[sg];
        }
    }
    __syncthreads();
    if (kg == 0) {
        u16* ob = newv + (size_t)b * LL * 512 + h * 64;
        const float* rg = xch + qg * (68 * 64);
#pragma unroll
        for (int sg = 0; sg < 4; ++sg) {
            float dsum = dnm[sg];
#pragma unroll
            for (int p = 0; p < 3; ++p) dsum += rg[p * XRG + ((64 + sg) << 6) + lane];
            float inv = 1.f / dsum;
            const size_t orow = (size_t)(q0 + sg * 16 + l16) * 512 + quad * 4;
#pragma unroll
            for (int dt = 0; dt < 4; ++dt) {
                float o[4];
#pragma unroll
                for (int r = 0; r < 4; ++r) {
                    o[r] = oacc[sg][dt][r];
#pragma unroll
                    for (int p = 0; p < 3; ++p)
                        o[r] += rg[p * XRG + ((sg * 16 + dt * 4 + r) << 6) + lane];
                }
                unsigned lo = (unsigned)f2u(o[0] * inv) | ((unsigned)f2u(o[1] * inv) << 16);
                unsigned hi = (unsigned)f2u(o[2] * inv) | ((unsigned)f2u(o[3] * inv) << 16);
                uint2 val; val.x = lo; val.y = hi;
                *(uint2*)(ob + orow + dt * 16) = val;
            }
        }
    }
#undef XRG
}

// -------------------------------------------------------------------------
// Kernel 3: MFMA FC + swish + residual + layernorm, fused — 512 threads
// (8 waves, 64 cols each => 2 waves/SIMD). The block's 16 newv rows are
// staged ONCE into LDS via global_load_lds (linear dest + inverse-XOR
// source, XOR on read => <=2-way banks). R5-verified.
// -------------------------------------------------------------------------
__global__ __launch_bounds__(512) void fc_ln_mfma_kernel(
    const u16* __restrict__ newv,    // [4096][512] bf16
    const u16* __restrict__ fcw,     // [512][512] bf16
    const u16* __restrict__ fcb,     // [512]
    const u16* __restrict__ xp,      // [B][2050][512] padded bf16
    const u16* __restrict__ xraw,    // raw x input (dtype detect)
    void* __restrict__ out)          // bf16 or f32 per flag
{
    const int flag = detect_flag(xraw);
    const int l0 = blockIdx.x * 16;
    const int tid  = threadIdx.x;
    const int wave = tid >> 6;           // 0..7
    const int lane = tid & 63;
    const int quad = lane >> 4;
    const int l16  = lane & 15;
    const int col0 = wave * 64;

    const int bb_ = l0 >> 11;   // batch (16-row tiles never straddle)
    const size_t xbase = ((size_t)(bb_ * 2050 + (l0 & 2047) + 1)) * 512;

    __shared__ u16 As[16][512];          // 16 KB staged newv rows
    __shared__ float psum[8][16], psq[8][16];

    // stage: wave w stages rows w and w+8 (64 x 16B chunks per row).
    // LDS chunk c of row holds global chunk c ^ (row&7).
#pragma unroll
    for (int r = 0; r < 2; ++r) {
        const int row = wave + r * 8;
        gld_lds16(newv + (size_t)(l0 + row) * 512 + ((lane ^ (row & 7)) * 8),
                  &As[row][0]);
    }
    __syncthreads();   // drains vmcnt

    // aF[kc] = rows l16, cols kc*32 + quad*8 (chunk p = kc*4+quad, XOR'd)
    short8v aF[16];
#pragma unroll
    for (int kc = 0; kc < 16; ++kc)
        aF[kc] = *(const short8v*)&As[l16][(((kc * 4 + quad)) ^ (l16 & 7)) * 8];

    float4v acc[4];
#pragma unroll
    for (int nt = 0; nt < 4; ++nt) acc[nt] = (float4v){0.f, 0.f, 0.f, 0.f};

#pragma unroll
    for (int nt = 0; nt < 4; ++nt) {
        const u16* brow = fcw + (size_t)(col0 + nt * 16 + l16) * 512 + quad * 8;
#pragma unroll
        for (int kc = 0; kc < 16; ++kc) {
            short8v bF = *(const short8v*)(brow + kc * 32);
            acc[nt] = __builtin_amdgcn_mfma_f32_16x16x32_bf16(aF[kc], bF, acc[nt], 0, 0, 0);
        }
    }

    float z[4][4];
    float rs[4] = {0.f, 0.f, 0.f, 0.f}, rq[4] = {0.f, 0.f, 0.f, 0.f};
#pragma unroll
    for (int nt = 0; nt < 4; ++nt) {
        int col = col0 + nt * 16 + l16;
        float bb = b2f(fcb[col]);
#pragma unroll
        for (int r = 0; r < 4; ++r) {
            int row = quad * 4 + r;
            float y = acc[nt][r] + bb;
            float sw = y / (1.f + __expf(-y));    // swish
            float xv = b2f(xp[xbase + (size_t)row * 512 + col]);
            float zz = xv * 2.f + sw;
            z[nt][r] = zz;
            rs[r] += zz;
            rq[r] += zz * zz;
        }
    }
#pragma unroll
    for (int msk = 1; msk <= 8; msk <<= 1)
#pragma unroll
        for (int r = 0; r < 4; ++r) {
            rs[r] += __shfl_xor(rs[r], msk);
            rq[r] += __shfl_xor(rq[r], msk);
        }
    if (l16 == 0) {
#pragma unroll
        for (int r = 0; r < 4; ++r) {
            psum[wave][quad * 4 + r] = rs[r];
            psq[wave][quad * 4 + r]  = rq[r];
        }
    }
    __syncthreads();

    float mu[4], inv[4];
#pragma unroll
    for (int r = 0; r < 4; ++r) {
        int row = quad * 4 + r;
        float s = 0.f, q = 0.f;
#pragma unroll
        for (int w = 0; w < 8; ++w) { s += psum[w][row]; q += psq[w][row]; }
        float m = s * (1.f / 512.f);
        float var = q * (1.f / 512.f) - m * m;
        mu[r] = m;
        inv[r] = rsqrtf(var + 1e-5f);
    }

#pragma unroll
    for (int nt = 0; nt < 4; ++nt) {
        int col = col0 + nt * 16 + l16;
#pragma unroll
        for (int r = 0; r < 4; ++r) {
            int row = quad * 4 + r;
            float val = (z[nt][r] - mu[r]) * inv[r];
            if (flag) ((float*)out)[(size_t)(l0 + row) * 512 + col] = val;
            else      ((u16*)out)[(size_t)(l0 + row) * 512 + col] = f2u(val);
        }
    }
}

extern "C" void kernel_launch(void* const* d_in, const int* in_sizes, int n_in,
                              void* d_out, int out_size, void* d_ws, size_t ws_size,
                              hipStream_t stream) {
    (void)in_sizes; (void)n_in; (void)out_size; (void)ws_size;

    char* ws = (char*)d_ws;
    u16* xp   = (u16*)(ws + 256);        // [2][2050][512] 4,198,400 B -> ends 4,198,656
    u16* wtc  = (u16*)(ws + 4198656);    // [1536][1536] 4,718,592 B  -> ends 8,917,248
    u16* bc   = (u16*)(ws + 8917248);    // 3,072 B  -> ends 8,920,320
    u16* fwc  = (u16*)(ws + 8920320);    // 524,288 B -> ends 9,444,608
    u16* fbc  = (u16*)(ws + 9444608);    // 1,024 B  -> ends 9,445,632
    u16* qkb  = (u16*)(ws + 9445632);    // [16][2][2048][64] = 8 MB -> ends 17,834,240
    u16* vb   = (u16*)(ws + 17834240);   // [16][64][2048]    = 4 MB -> ends 22,028,544
    u16* nvc  = (u16*)(ws + 22028544);   // [2][2048][512]    = 4 MB -> ends 26,222,848

    // unified prep: 1024 (xpad) + 192 (convw via LDS) + 129 (small) = 1345
    prep_kernel<<<dim3(1345), dim3(256), 0, stream>>>(
        d_in[0], d_in[1], d_in[2], d_in[3], d_in[4],
        xp, wtc, bc, fwc, fbc);

    conv_mfma_kernel<<<dim3(256), dim3(512), 0, stream>>>(xp, wtc, bc, qkb, vb);
    attn_mfma_kernel<<<dim3(256), dim3(512), 0, stream>>>(qkb, vb, nvc);
    fc_ln_mfma_kernel<<<dim3(256), dim3(512), 0, stream>>>(
        nvc, fwc, fbc, xp, (const u16*)d_in[0], d_out);
}

// Round 8
// 143.396 us; speedup vs baseline: 1.0416x; 1.0167x over previous
//
#include <hip/hip_runtime.h>
#include <hip/hip_bf16.h>

// Problem constants
#define BB 2
#define LL 2048
#define DD 512
#define HH 8
#define HDM 64
#define SCALE 0.022097086912079608f    // 1/sqrt(2048)
#define QSCALE 0.03187935766f          // SCALE * log2(e)  (exp2-domain softmax)

typedef __hip_bfloat16 bf16;
typedef unsigned short u16;
typedef __attribute__((ext_vector_type(8))) short short8v;   // 8 bf16 (4 VGPRs)
typedef __attribute__((ext_vector_type(4))) float float4v;   // 4 fp32 acc

// Input element counts
#define XN  2097152    // 2*2048*512
#define WN  2359296    // 1536*512*3
#define BN  1536
#define FWN 262144     // 512*512
#define FBN 512

__device__ __forceinline__ float b2f(u16 u) {
    return __uint_as_float(((unsigned int)u) << 16);
}
__device__ __forceinline__ u16 f2u(float f) {
    bf16 h = __float2bfloat16(f);
    u16 r;
    __builtin_memcpy(&r, &h, 2);
    return r;
}
__device__ __forceinline__ uint4 pack8(const float* f) {
    uint4 p;
    p.x = (unsigned)f2u(f[0]) | ((unsigned)f2u(f[1]) << 16);
    p.y = (unsigned)f2u(f[2]) | ((unsigned)f2u(f[3]) << 16);
    p.z = (unsigned)f2u(f[4]) | ((unsigned)f2u(f[5]) << 16);
    p.w = (unsigned)f2u(f[6]) | ((unsigned)f2u(f[7]) << 16);
    return p;
}

// async 16-B global -> LDS copy (lds dest = wave-uniform base + lane*16)
__device__ __forceinline__ void gld_lds16(const u16* g, u16* l) {
    __builtin_amdgcn_global_load_lds(
        (const __attribute__((address_space(1))) unsigned int*)g,
        (__attribute__((address_space(3))) unsigned int*)l, 16, 0, 0);
}

// dtype detect (f32 vs bf16 inputs), computed locally per wave — all waves
// read the same first 256 half-words of raw x, so result is uniform and
// deterministic across all blocks/kernels.
__device__ __forceinline__ int detect_flag(const u16* __restrict__ xraw) {
    int bad = 0;
    int lane = threadIdx.x & 63;
    for (int i = lane; i < 256; i += 64) {
        float v = b2f(xraw[i]);
        if (!(fabsf(v) < 100.f)) bad = 1;   // catches NaN too
    }
    return (__ballot(bad) != 0ull) ? 1 : 0;
}

__device__ __forceinline__ void conv8(const void* src, u16* dst, size_t i, int flag) {
    if (flag) {
        const float* s = (const float*)src;
        float f[8];
        float4 a = *(const float4*)(s + i);
        float4 b = *(const float4*)(s + i + 4);
        f[0] = a.x; f[1] = a.y; f[2] = a.z; f[3] = a.w;
        f[4] = b.x; f[5] = b.y; f[6] = b.z; f[7] = b.w;
        *(uint4*)(dst + i) = pack8(f);
    } else {
        *(uint4*)(dst + i) = *(const uint4*)((const u16*)src + i);
    }
}

// -------------------------------------------------------------------------
// Kernel 0: unified prep — one launch, block-range branch:
//   [0,1024)    : x -> zero-guard-padded xp[B][2050][512] (+ guard rows)
//   [1024,1216) : cnn_w canonicalize + transpose via LDS (coalesced loads)
//   [1216,1345) : cnn_b + fc_w + fc_b converts
// -------------------------------------------------------------------------
__global__ __launch_bounds__(256) void prep_kernel(
    const void* __restrict__ xsrc, const void* __restrict__ wsrc,
    const void* __restrict__ bsrc, const void* __restrict__ fwsrc,
    const void* __restrict__ fbsrc,
    u16* __restrict__ xp, u16* __restrict__ wt,
    u16* __restrict__ bc, u16* __restrict__ fwc, u16* __restrict__ fbc)
{
    const int flag = detect_flag((const u16*)xsrc);
    const int bid = blockIdx.x;

    if (bid < 1024) {
        // ---- xpad ----
        int idx = bid * 256 + threadIdx.x;           // octet id, < 2*2048*64
        if (idx < 256) {
            int b2  = idx >> 7;
            int r2  = (idx >> 6) & 1;
            int c82 = (idx & 63) * 8;
            size_t off = ((size_t)(b2 * 2050 + (r2 ? 2049 : 0))) * 512 + c82;
            uint4 z = {0u, 0u, 0u, 0u};
            *(uint4*)(xp + off) = z;
        }
        int b   = idx / (LL * 64);
        int rem = idx - b * (LL * 64);
        int l   = rem >> 6;
        int c8  = (rem & 63) * 8;
        size_t si = ((size_t)(b * LL + l)) * 512 + c8;
        size_t di = ((size_t)(b * 2050 + l + 1)) * 512 + c8;
        if (flag) {
            const float* s = (const float*)xsrc;
            float f[8];
            float4 a = *(const float4*)(s + si);
            float4 bq = *(const float4*)(s + si + 4);
            f[0] = a.x; f[1] = a.y; f[2] = a.z; f[3] = a.w;
            f[4] = bq.x; f[5] = bq.y; f[6] = bq.z; f[7] = bq.w;
            *(uint4*)(xp + di) = pack8(f);
        } else {
            *(uint4*)(xp + di) = *(const uint4*)((const u16*)xsrc + si);
        }
    } else if (bid < 1216) {
        // ---- convw via LDS transpose: 8 o-rows per block, coalesced ----
        __shared__ u16 wl[8 * 1536];                 // 24 KB, [row][i*3+k]
        const int t  = threadIdx.x;
        const int o0 = (bid - 1024) * 8;
        if (flag) {
            const float4* s4 = (const float4*)((const float*)wsrc + (size_t)o0 * 1536);
#pragma unroll
            for (int v = 0; v < 12; ++v) {           // 3072 float4 total
                int i4 = v * 256 + t;
                float4 q = s4[i4];
                uint2 p;
                p.x = (unsigned)f2u(q.x) | ((unsigned)f2u(q.y) << 16);
                p.y = (unsigned)f2u(q.z) | ((unsigned)f2u(q.w) << 16);
                *(uint2*)&wl[i4 * 4] = p;
            }
        } else {
            const uint4* s8 = (const uint4*)((const u16*)wsrc + (size_t)o0 * 1536);
#pragma unroll
            for (int v = 0; v < 6; ++v) {            // 1536 uint4 total
                int i8 = v * 256 + t;
                *(uint4*)&wl[i8 * 8] = s8[i8];
            }
        }
        __syncthreads();
#pragma unroll
        for (int v = 0; v < 6; ++v) {                // 1536 output octets
            int oct = v * 256 + t;
            int row = oct / 192;
            int rem = oct - row * 192;
            int k   = rem >> 6;
            int i8  = rem & 63;
            u16 tmp[8];
#pragma unroll
            for (int j = 0; j < 8; ++j) tmp[j] = wl[row * 1536 + (i8 * 8 + j) * 3 + k];
            uint4 val;
            val.x = (unsigned)tmp[0] | ((unsigned)tmp[1] << 16);
            val.y = (unsigned)tmp[2] | ((unsigned)tmp[3] << 16);
            val.z = (unsigned)tmp[4] | ((unsigned)tmp[5] << 16);
            val.w = (unsigned)tmp[6] | ((unsigned)tmp[7] << 16);
            *(uint4*)(wt + (size_t)(o0 + row) * 1536 + k * 512 + i8 * 8) = val;
        }
    } else {
        // ---- small converts ----
        int o = (bid - 1216) * 256 + threadIdx.x;    // octet id
        if (o < BN / 8) {
            conv8(bsrc, bc, (size_t)o * 8, flag);
        } else if (o < BN / 8 + FWN / 8) {
            conv8(fwsrc, fwc, (size_t)(o - BN / 8) * 8, flag);
        } else if (o < BN / 8 + FWN / 8 + FBN / 8) {
            conv8(fbsrc, fbc, (size_t)(o - BN / 8 - FWN / 8) * 8, flag);
        }
    }
}

// -------------------------------------------------------------------------
// Kernel 1: conv GEMM — 128x192 x 512 threads, 256 blocks (R7-verified
// shape) with a T4 counted-vmcnt K-loop: prologue stages chunks 0,1; each
// iteration waits vmcnt(5) (own 5 loads of the current buffer; next
// chunk's 5 stay in flight across the barrier), ds_reads all frags,
// lgkmcnt(0)+barrier (all waves done reading), THEN issues stage(kc+2)
// into the just-read buffer and runs the MFMA cluster under the in-flight
// loads. vmcnt never drains to 0 in the main loop (m218 pattern). MFMA
// order/addressing/swizzle identical to R7 => bitwise-same accumulation.
// -------------------------------------------------------------------------
__global__ __launch_bounds__(512) void conv_mfma_kernel(
    const u16* __restrict__ xp,     // [B][2050][512] padded bf16
    const u16* __restrict__ wt,     // [1536][1536] = [o][k*512+i]
    const u16* __restrict__ bias,   // [1536]
    u16* __restrict__ qkbuf,        // [B*H][2][L][64]
    u16* __restrict__ vbuf)         // [B*H][64][L] (key-permuted)
{
    __shared__ u16 smem[40960];     // 81920 B
    u16* Asb = smem;                // [2][128][64] unpadded, swizzled (32 KB)
    u16* Bsb = smem + 16384;        // [2][192][64] unpadded, swizzled (48 KB)
#define OTS 204
    u16* OT  = smem;                // [128][204] aliased after final sync

    const int blk = blockIdx.x;          // rt*8 + ct
    const int rt = blk >> 3;
    const int ct = blk & 7;
    const int b  = rt >> 4;
    const int l0 = (rt & 15) * 128;
    const int tid  = threadIdx.x;
    const int wave = tid >> 6;           // 0..7
    const int lane = tid & 63;
    const int quad = lane >> 4;
    const int l16  = lane & 15;
    const int e7   = l16 & 7;
    const int wm = wave >> 2;            // M half (rows wm*64)
    const int wn = wave & 3;             // N quarter (cols wn*48)

    float4v acc[4][3];
#pragma unroll
    for (int mt = 0; mt < 4; ++mt)
#pragma unroll
        for (int nt = 0; nt < 3; ++nt) acc[mt][nt] = (float4v){0.f, 0.f, 0.f, 0.f};

    const int lrow = lane >> 3;          // 0..7
    const int g8   = (((lane & 7) ^ lrow)) * 8;
    auto stage = [&](int kc, int buf) {
        const int slab = kc >> 3;                // conv tap k (0..2)
        const int i0   = (kc & 7) * 64;          // input-channel slice
        // A: 128 rows, wave w stages rows w*16 + j*8 (+lrow)
#pragma unroll
        for (int j = 0; j < 2; ++j) {
            const int r0 = wave * 16 + j * 8;
            gld_lds16(xp + ((size_t)(b * 2050 + l0 + r0 + slab + lrow)) * 512 + i0 + g8,
                      Asb + (size_t)(buf * 128 + r0) * 64);
        }
        // B: 192 rows, wave w stages rows w*24 + j*8 (+lrow)
#pragma unroll
        for (int j = 0; j < 3; ++j) {
            const int r0 = wave * 24 + j * 8;
            gld_lds16(wt + ((size_t)(ct * 192 + r0 + lrow)) * 1536 + kc * 64 + g8,
                      Bsb + (size_t)(buf * 192 + r0) * 64);
        }
    };

    // per-iteration body: read frags of buf cur, fence, stage kc+2, MFMA
    auto kstep = [&](int kc, bool prefetch) {
        const int cur = kc & 1;
        short8v aF[2][4], bF[2][3];
#pragma unroll
        for (int half = 0; half < 2; ++half) {
            const int p = ((half * 4 + quad) ^ e7) * 8;   // swizzled chunk
#pragma unroll
            for (int mt = 0; mt < 4; ++mt)
                aF[half][mt] = *(const short8v*)&Asb[(size_t)(cur * 128 + wm * 64 + mt * 16 + l16) * 64 + p];
#pragma unroll
            for (int nt = 0; nt < 3; ++nt)
                bF[half][nt] = *(const short8v*)&Bsb[(size_t)(cur * 192 + wn * 48 + nt * 16 + l16) * 64 + p];
        }
        asm volatile("s_waitcnt lgkmcnt(0)" ::: "memory");  // my reads done
        asm volatile("s_barrier" ::: "memory");             // all waves' reads done
        if (prefetch) stage(kc + 2, cur);                   // overwrite now safe
#pragma unroll
        for (int half = 0; half < 2; ++half)
#pragma unroll
            for (int mt = 0; mt < 4; ++mt)
#pragma unroll
                for (int nt = 0; nt < 3; ++nt)
                    acc[mt][nt] = __builtin_amdgcn_mfma_f32_16x16x32_bf16(
                        aF[half][mt], bF[half][nt], acc[mt][nt], 0, 0, 0);
    };

    stage(0, 0);
    stage(1, 1);

    for (int kc = 0; kc < 23; ++kc) {
        // buf (kc&1) ready once my 5 loads for chunk kc land; chunk kc+1's
        // 5 loads stay in flight across the barrier.
        asm volatile("s_waitcnt vmcnt(5)" ::: "memory");
        asm volatile("s_barrier" ::: "memory");
        kstep(kc, kc < 22);
    }
    {   // kc = 23: nothing left in flight to preserve
        asm volatile("s_waitcnt vmcnt(0)" ::: "memory");
        asm volatile("s_barrier" ::: "memory");
        kstep(23, false);
    }

    // ---- epilogue stage 1: bias+swish(+QSCALE) in regs -> OT [128 l][192 o]
    __syncthreads();   // all LDS tile reads done; safe to alias as OT
    {
#pragma unroll
        for (int nt = 0; nt < 3; ++nt) {
            int oc = wn * 48 + nt * 16 + l16;           // tile-local col (0..191)
            float bb = b2f(bias[ct * 192 + oc]);
#pragma unroll
            for (int mt = 0; mt < 4; ++mt)
#pragma unroll
                for (int r = 0; r < 4; ++r) {
                    int lr = wm * 64 + mt * 16 + quad * 4 + r;   // tile-local row
                    float y = acc[mt][nt][r] + bb;
                    y = y / (1.f + __expf(-y));                  // swish
                    if (oc < 64) y *= QSCALE;                    // Q group: fold scale*log2e
                    OT[lr * OTS + oc] = f2u(y);
                }
        }
    }
    __syncthreads();

    // ---- epilogue stage 2: coalesced write-out per 64-col group (g = t)
    const int bh = b * HH + ct;          // 192 cols = head ct's {q,k,v}
#pragma unroll
    for (int g = 0; g < 3; ++g) {
        if (g != 2) {
            u16* base = qkbuf + ((size_t)((bh * 2 + g) * LL + l0)) * HDM;
#pragma unroll
            for (int it = 0; it < 2; ++it) {
                int idx = it * 512 + tid;       // 0..1023
                int l   = idx >> 3;             // 0..127
                int d8  = (idx & 7) * 8;        // 0..56
                uint4 val = *(const uint4*)&OT[l * OTS + g * 64 + d8];
                *(uint4*)(base + (size_t)l * HDM + d8) = val;
            }
        } else {
            u16* base = vbuf + ((size_t)(bh * HDM)) * LL + l0;
#pragma unroll
            for (int it = 0; it < 2; ++it) {
                int idx = it * 512 + tid;       // 0..1023
                int dd  = idx >> 4;             // 0..63
                int p   = idx & 15;             // 8-row group within 128 tile
                int l8  = p * 8;
                u16 tmp[8];
#pragma unroll
                for (int j = 0; j < 8; ++j) tmp[j] = OT[(l8 + j) * OTS + g * 64 + dd];
                // tile-interleaved key permute within each 32-key group:
                // orig w -> n = 8*((w>>2)&3) + 4*(w>>4) + (w&3)
                int a32 = p >> 2;                // 32-key group
                int pb_ = p & 3;
                int q2  = (2 * pb_) & 3;
                int h2  = pb_ >> 1;
                int n0  = 32 * a32 + 8 * q2 + 4 * h2;   // j=0..3 run
                uint2 v0, v1;
                v0.x = (unsigned)tmp[0] | ((unsigned)tmp[1] << 16);
                v0.y = (unsigned)tmp[2] | ((unsigned)tmp[3] << 16);
                v1.x = (unsigned)tmp[4] | ((unsigned)tmp[5] << 16);
                v1.y = (unsigned)tmp[6] | ((unsigned)tmp[7] << 16);
                *(uint2*)(base + (size_t)dd * LL + n0)     = v0;   // j=0..3
                *(uint2*)(base + (size_t)dd * LL + n0 + 8) = v1;   // j=4..7
            }
        }
    }
#undef OTS
}

// -------------------------------------------------------------------------
// Kernel 2: MFMA flash attention — quad-Q (64 queries/wave: every K/V LDS
// fragment read feeds 4 subgroups' MFMAs) + 4-way split-K (static softmax
// => partials purely additive; combine = 3 writer groups + kg0 accumulate).
// 256 blocks x 512 threads: wave = (kg = w>>1, qg = w&1); each kg
// double-buffers its own 64-key K[64][64]/V[64][64] tiles (128 KB LDS,
// 1 block/CU, 2 waves/SIMD). Register-resident P^T layout and key-permuted
// V consumption identical to the R3-verified dual-Q form. R6-verified.
// -------------------------------------------------------------------------
__global__ __launch_bounds__(512) void attn_mfma_kernel(
    const u16* __restrict__ qk,    // [B*H][2][L][64]
    const u16* __restrict__ v,     // [B*H][64][L] key-permuted
    u16* __restrict__ newv)        // [B][L][512]
{
    __shared__ u16 smem[65536];                                   // 128 KB pool
    u16 (*kts)[2][64][64] = (u16 (*)[2][64][64])smem;             // [kg][buf][key][d] 64 KB
    u16 (*vts)[2][64][64] = (u16 (*)[2][64][64])(smem + 32768);   // [kg][buf][d][key] 64 KB

    // bijective XCD swizzle (256 % 8 == 0): 16 blocks of one bh -> 2 bh/XCD
    const int lb = ((blockIdx.x & 7) << 5) + (blockIdx.x >> 3);
    const int bh = lb >> 4;              // b*8 + h
    const int qc = lb & 15;              // 128-query chunk
    const int b  = bh >> 3;
    const int h  = bh & 7;
    const int tid  = threadIdx.x;
    const int wave = tid >> 6;           // 0..7
    const int kg   = wave >> 1;          // split-K group 0..3
    const int qg   = wave & 1;           // query group 0..1
    const int lane = tid & 63;
    const int quad = lane >> 4;
    const int l16  = lane & 15;
    const int e7   = l16 & 7;

    const u16* qbase = qk + ((size_t)(bh * 2 + 0)) * LL * HDM;
    const u16* kbase = qk + ((size_t)(bh * 2 + 1)) * LL * HDM;
    const u16* vbase = v + (size_t)bh * HDM * LL;

    const int q0 = qc * 128 + qg * 64;   // wave's 64 queries (4 subgroups of 16)

    // Q as B-frag per subgroup: lane l16 = query col, k-slot quad*8+j = d
    short8v qfrag[4][2];
#pragma unroll
    for (int sg = 0; sg < 4; ++sg) {
        const u16* qr = qbase + (size_t)(q0 + sg * 16 + l16) * HDM + quad * 8;
        qfrag[sg][0] = *(const short8v*)(qr);
        qfrag[sg][1] = *(const short8v*)(qr + 32);
    }

    // ones-row A-frag for col-sum MFMA: A[row=l16][k]=1 iff row==0
    short8v vones;
    {
        short o1 = (l16 == 0) ? (short)0x3F80 : (short)0;
#pragma unroll
        for (int j = 0; j < 8; ++j) vones[j] = o1;
    }

    float4v oacc[4][4];                  // [sg][dt] out^T rows d, col=query l16
    float4v lacc[4];
#pragma unroll
    for (int sg = 0; sg < 4; ++sg) {
        lacc[sg] = (float4v){0.f, 0.f, 0.f, 0.f};
#pragma unroll
        for (int dt = 0; dt < 4; ++dt) oacc[sg][dt] = (float4v){0.f, 0.f, 0.f, 0.f};
    }

    // staging: 2 waves of a kgroup (qg 0/1) cooperate on K 64x64 and V 64x64.
    // LDS[row][chunk c] holds global chunk c ^ (row&7)  (row&7 == lane>>3).
    const int rw8 = lane >> 3;            // 0..7
    const int sw8 = ((lane & 7) ^ rw8) * 8;
    auto stage = [&](int ic, int buf) {
        const int m0 = ic * 64;
#pragma unroll
        for (int r = 0; r < 4; ++r) {
            const int row0 = r * 16 + qg * 8;
            gld_lds16(kbase + (size_t)(m0 + row0 + rw8) * HDM + sw8,
                      &kts[kg][buf][row0][0]);
            gld_lds16(vbase + (size_t)(row0 + rw8) * LL + m0 + sw8,
                      &vts[kg][buf][row0][0]);
        }
    };

    stage(kg, 0);   // kgroup kg handles chunks 4*i + kg, i = 0..7

    for (int i = 0; i < 8; ++i) {
        const int cur = i & 1;
        __syncthreads();   // drains vmcnt -> chunk staged; prev reads done

        if (i < 7) stage(4 * (i + 1) + kg, 1 - cur);

        // S^T = K.Q^T per sg; exp2 immediately (keeps s-live-range short)
        unsigned pk[4][4][2];
#pragma unroll
        for (int mt = 0; mt < 4; ++mt) {
            short8v b0 = *(const short8v*)&kts[kg][cur][mt * 16 + l16][((quad) ^ e7) * 8];
            short8v b1 = *(const short8v*)&kts[kg][cur][mt * 16 + l16][((quad + 4) ^ e7) * 8];
#pragma unroll
            for (int sg = 0; sg < 4; ++sg) {
                float4v t = (float4v){0.f, 0.f, 0.f, 0.f};
                t = __builtin_amdgcn_mfma_f32_16x16x32_bf16(b0, qfrag[sg][0], t, 0, 0, 0);
                t = __builtin_amdgcn_mfma_f32_16x16x32_bf16(b1, qfrag[sg][1], t, 0, 0, 0);
                float p0 = __builtin_amdgcn_exp2f(t[0]);
                float p1 = __builtin_amdgcn_exp2f(t[1]);
                float p2 = __builtin_amdgcn_exp2f(t[2]);
                float p3 = __builtin_amdgcn_exp2f(t[3]);
                pk[sg][mt][0] = (unsigned)f2u(p0) | ((unsigned)f2u(p1) << 16);
                pk[sg][mt][1] = (unsigned)f2u(p2) | ((unsigned)f2u(p3) << 16);
            }
        }

        // 2 PV K=32 blocks per 64-key chunk; each V A-frag read feeds 4 sg
#pragma unroll
        for (int mu = 0; mu < 2; ++mu) {
            short8v pb[4];
#pragma unroll
            for (int sg = 0; sg < 4; ++sg) {
                union { short8v v8; unsigned u[4]; } U;
                U.u[0] = pk[sg][2 * mu][0];
                U.u[1] = pk[sg][2 * mu][1];
                U.u[2] = pk[sg][2 * mu + 1][0];
                U.u[3] = pk[sg][2 * mu + 1][1];
                pb[sg] = U.v8;
                lacc[sg] = __builtin_amdgcn_mfma_f32_16x16x32_bf16(vones, pb[sg], lacc[sg], 0, 0, 0);
            }
#pragma unroll
            for (int dt = 0; dt < 4; ++dt) {
                short8v va = *(const short8v*)&vts[kg][cur][dt * 16 + l16][((mu * 4 + quad) ^ e7) * 8];
#pragma unroll
                for (int sg = 0; sg < 4; ++sg)
                    oacc[sg][dt] = __builtin_amdgcn_mfma_f32_16x16x32_bf16(va, pb[sg], oacc[sg][dt], 0, 0, 0);
            }
        }
    }

    // denom for query l16 sits in lacc[sg][0] of lane l16 (row 0 of D)
    float dnm[4];
#pragma unroll
    for (int sg = 0; sg < 4; ++sg) dnm[sg] = __shfl(lacc[sg][0], l16);

    // split-K combine: static softmax => oacc/denoms add directly.
    // xch: 3 regions (kg 1..3) x [qg 2][68 rows][64 lanes] f32 = 104,448 B
    __syncthreads();   // all tile reads done; alias pool as exchange
    float* xch = (float*)smem;
#define XRG (2 * 68 * 64)
    if (kg > 0) {
        float* rg = xch + (kg - 1) * XRG + qg * (68 * 64);
#pragma unroll
        for (int sg = 0; sg < 4; ++sg) {
#pragma unroll
            for (int dt = 0; dt < 4; ++dt)
#pragma unroll
                for (int r = 0; r < 4; ++r)
                    rg[((sg * 16 + dt * 4 + r) << 6) + lane] = oacc[sg][dt][r];
            rg[((64 + sg) << 6) + lane] = dnm[sg];
        }
    }
    __syncthreads();
    if (kg == 0) {
        u16* ob = newv + (size_t)b * LL * 512 + h * 64;
        const float* rg = xch + qg * (68 * 64);
#pragma unroll
        for (int sg = 0; sg < 4; ++sg) {
            float dsum = dnm[sg];
#pragma unroll
            for (int p = 0; p < 3; ++p) dsum += rg[p * XRG + ((64 + sg) << 6) + lane];
            float inv = 1.f / dsum;
            const size_t orow = (size_t)(q0 + sg * 16 + l16) * 512 + quad * 4;
#pragma unroll
            for (int dt = 0; dt < 4; ++dt) {
                float o[4];
#pragma unroll
                for (int r = 0; r < 4; ++r) {
                    o[r] = oacc[sg][dt][r];
#pragma unroll
                    for (int p = 0; p < 3; ++p)
                        o[r] += rg[p * XRG + ((sg * 16 + dt * 4 + r) << 6) + lane];
                }
                unsigned lo = (unsigned)f2u(o[0] * inv) | ((unsigned)f2u(o[1] * inv) << 16);
                unsigned hi = (unsigned)f2u(o[2] * inv) | ((unsigned)f2u(o[3] * inv) << 16);
                uint2 val; val.x = lo; val.y = hi;
                *(uint2*)(ob + orow + dt * 16) = val;
            }
        }
    }
#undef XRG
}

// -------------------------------------------------------------------------
// Kernel 3: MFMA FC + swish + residual + layernorm, fused — 512 threads
// (8 waves, 64 cols each => 2 waves/SIMD). The block's 16 newv rows are
// staged ONCE into LDS via global_load_lds (linear dest + inverse-XOR
// source, XOR on read => <=2-way banks). R5-verified.
// -------------------------------------------------------------------------
__global__ __launch_bounds__(512) void fc_ln_mfma_kernel(
    const u16* __restrict__ newv,    // [4096][512] bf16
    const u16* __restrict__ fcw,     // [512][512] bf16
    const u16* __restrict__ fcb,     // [512]
    const u16* __restrict__ xp,      // [B][2050][512] padded bf16
    const u16* __restrict__ xraw,    // raw x input (dtype detect)
    void* __restrict__ out)          // bf16 or f32 per flag
{
    const int flag = detect_flag(xraw);
    const int l0 = blockIdx.x * 16;
    const int tid  = threadIdx.x;
    const int wave = tid >> 6;           // 0..7
    const int lane = tid & 63;
    const int quad = lane >> 4;
    const int l16  = lane & 15;
    const int col0 = wave * 64;

    const int bb_ = l0 >> 11;   // batch (16-row tiles never straddle)
    const size_t xbase = ((size_t)(bb_ * 2050 + (l0 & 2047) + 1)) * 512;

    __shared__ u16 As[16][512];          // 16 KB staged newv rows
    __shared__ float psum[8][16], psq[8][16];

    // stage: wave w stages rows w and w+8 (64 x 16B chunks per row).
    // LDS chunk c of row holds global chunk c ^ (row&7).
#pragma unroll
    for (int r = 0; r < 2; ++r) {
        const int row = wave + r * 8;
        gld_lds16(newv + (size_t)(l0 + row) * 512 + ((lane ^ (row & 7)) * 8),
                  &As[row][0]);
    }
    __syncthreads();   // drains vmcnt

    // aF[kc] = rows l16, cols kc*32 + quad*8 (chunk p = kc*4+quad, XOR'd)
    short8v aF[16];
#pragma unroll
    for (int kc = 0; kc < 16; ++kc)
        aF[kc] = *(const short8v*)&As[l16][(((kc * 4 + quad)) ^ (l16 & 7)) * 8];

    float4v acc[4];
#pragma unroll
    for (int nt = 0; nt < 4; ++nt) acc[nt] = (float4v){0.f, 0.f, 0.f, 0.f};

#pragma unroll
    for (int nt = 0; nt < 4; ++nt) {
        const u16* brow = fcw + (size_t)(col0 + nt * 16 + l16) * 512 + quad * 8;
#pragma unroll
        for (int kc = 0; kc < 16; ++kc) {
            short8v bF = *(const short8v*)(brow + kc * 32);
            acc[nt] = __builtin_amdgcn_mfma_f32_16x16x32_bf16(aF[kc], bF, acc[nt], 0, 0, 0);
        }
    }

    float z[4][4];
    float rs[4] = {0.f, 0.f, 0.f, 0.f}, rq[4] = {0.f, 0.f, 0.f, 0.f};
#pragma unroll
    for (int nt = 0; nt < 4; ++nt) {
        int col = col0 + nt * 16 + l16;
        float bb = b2f(fcb[col]);
#pragma unroll
        for (int r = 0; r < 4; ++r) {
            int row = quad * 4 + r;
            float y = acc[nt][r] + bb;
            float sw = y / (1.f + __expf(-y));    // swish
            float xv = b2f(xp[xbase + (size_t)row * 512 + col]);
            float zz = xv * 2.f + sw;
            z[nt][r] = zz;
            rs[r] += zz;
            rq[r] += zz * zz;
        }
    }
#pragma unroll
    for (int msk = 1; msk <= 8; msk <<= 1)
#pragma unroll
        for (int r = 0; r < 4; ++r) {
            rs[r] += __shfl_xor(rs[r], msk);
            rq[r] += __shfl_xor(rq[r], msk);
        }
    if (l16 == 0) {
#pragma unroll
        for (int r = 0; r < 4; ++r) {
            psum[wave][quad * 4 + r] = rs[r];
            psq[wave][quad * 4 + r]  = rq[r];
        }
    }
    __syncthreads();

    float mu[4], inv[4];
#pragma unroll
    for (int r = 0; r < 4; ++r) {
        int row = quad * 4 + r;
        float s = 0.f, q = 0.f;
#pragma unroll
        for (int w = 0; w < 8; ++w) { s += psum[w][row]; q += psq[w][row]; }
        float m = s * (1.f / 512.f);
        float var = q * (1.f / 512.f) - m * m;
        mu[r] = m;
        inv[r] = rsqrtf(var + 1e-5f);
    }

#pragma unroll
    for (int nt = 0; nt < 4; ++nt) {
        int col = col0 + nt * 16 + l16;
#pragma unroll
        for (int r = 0; r < 4; ++r) {
            int row = quad * 4 + r;
            float val = (z[nt][r] - mu[r]) * inv[r];
            if (flag) ((float*)out)[(size_t)(l0 + row) * 512 + col] = val;
            else      ((u16*)out)[(size_t)(l0 + row) * 512 + col] = f2u(val);
        }
    }
}

extern "C" void kernel_launch(void* const* d_in, const int* in_sizes, int n_in,
                              void* d_out, int out_size, void* d_ws, size_t ws_size,
                              hipStream_t stream) {
    (void)in_sizes; (void)n_in; (void)out_size; (void)ws_size;

    char* ws = (char*)d_ws;
    u16* xp   = (u16*)(ws + 256);        // [2][2050][512] 4,198,400 B -> ends 4,198,656
    u16* wtc  = (u16*)(ws + 4198656);    // [1536][1536] 4,718,592 B  -> ends 8,917,248
    u16* bc   = (u16*)(ws + 8917248);    // 3,072 B  -> ends 8,920,320
    u16* fwc  = (u16*)(ws + 8920320);    // 524,288 B -> ends 9,444,608
    u16* fbc  = (u16*)(ws + 9444608);    // 1,024 B  -> ends 9,445,632
    u16* qkb  = (u16*)(ws + 9445632);    // [16][2][2048][64] = 8 MB -> ends 17,834,240
    u16* vb   = (u16*)(ws + 17834240);   // [16][64][2048]    = 4 MB -> ends 22,028,544
    u16* nvc  = (u16*)(ws + 22028544);   // [2][2048][512]    = 4 MB -> ends 26,222,848

    // unified prep: 1024 (xpad) + 192 (convw via LDS) + 129 (small) = 1345
    prep_kernel<<<dim3(1345), dim3(256), 0, stream>>>(
        d_in[0], d_in[1], d_in[2], d_in[3], d_in[4],
        xp, wtc, bc, fwc, fbc);

    conv_mfma_kernel<<<dim3(256), dim3(512), 0, stream>>>(xp, wtc, bc, qkb, vb);
    attn_mfma_kernel<<<dim3(256), dim3(512), 0, stream>>>(qkb, vb, nvc);
    fc_ln_mfma_kernel<<<dim3(256), dim3(512), 0, stream>>>(
        nvc, fwc, fbc, xp, (const u16*)d_in[0], d_out);
}